// Round 12
// baseline (235.976 us; speedup 1.0000x reference)
//
#include <hip/hip_runtime.h>

// DTransformer forward (f32 in/out, f32 internal)
// B=2 S=512 D=256 H=8 DK=32 NK=16

namespace {
constexpr int kB = 2, kS = 512, kD = 256, kH = 8, kDK = 32, kNK = 16;
constexpr float kScale = 0.17677669529663687f;  // 1/sqrt(32)
constexpr int kPS = 520;                        // Pl row stride (bf16 elems)
constexpr int kSL = 528;                        // Sl row stride (f32): 16 segs x 33
}

typedef unsigned short u16;
typedef u16 u16x4 __attribute__((ext_vector_type(4)));
typedef u16 u16x8 __attribute__((ext_vector_type(8)));
typedef short s16x8 __attribute__((ext_vector_type(8)));
typedef float f32x4 __attribute__((ext_vector_type(4)));

__device__ __forceinline__ float bf2f(u16 u) { return __uint_as_float(((unsigned)u) << 16); }
__device__ __forceinline__ u16 f2bf(float f) {
    unsigned u = __float_as_uint(f);
    return (u16)((u + 0x7fffu + ((u >> 16) & 1u)) >> 16);
}
__device__ __forceinline__ void nt_store4(float* p, f32x4 v) {
    __builtin_nontemporal_store(v, (f32x4*)p);
}

__device__ __forceinline__ float wave_max64(float v) {
#pragma unroll
    for (int off = 32; off; off >>= 1) v = fmaxf(v, __shfl_xor(v, off));
    return v;
}
__device__ __forceinline__ float wave_sum64(float v) {
#pragma unroll
    for (int off = 32; off; off >>= 1) v += __shfl_xor(v, off);
    return v;
}

// Tiled transpose of 7 weight matrices [c][k] -> [k][c] (256x256 each), coalesced.
__global__ __launch_bounds__(256) void wt_kernel(const float* __restrict__ W0,
                                                 const float* __restrict__ W1,
                                                 const float* __restrict__ W2,
                                                 const float* __restrict__ W3,
                                                 const float* __restrict__ W4,
                                                 const float* __restrict__ W5,
                                                 const float* __restrict__ W6,
                                                 float* __restrict__ WT) {
    __shared__ float tile[32][33];
    const float* srcs[7] = {W0, W1, W2, W3, W4, W5, W6};
    const float* W = srcs[blockIdx.y];
    float* T = WT + (size_t)blockIdx.y * kD * kD;
    const int tx = blockIdx.x & 7, ty = blockIdx.x >> 3;
    const int t = threadIdx.x;
    {
        const int cl = t >> 3, kl = (t & 7) * 4;
        f32x4 v = *(const f32x4*)(W + (size_t)(ty * 32 + cl) * kD + tx * 32 + kl);
        tile[cl][kl] = v[0]; tile[cl][kl + 1] = v[1];
        tile[cl][kl + 2] = v[2]; tile[cl][kl + 3] = v[3];
    }
    __syncthreads();
    {
        const int kl = t >> 3, cl = (t & 7) * 4;
        f32x4 o = {tile[cl][kl], tile[cl + 1][kl], tile[cl + 2][kl], tile[cl + 3][kl]};
        *(f32x4*)(T + (size_t)(tx * 32 + kl) * kD + ty * 32 + cl) = o;
    }
}

// Batched projections: y=0: Q1 (scatter f32), y=1: Vtg1 (bf16 transposed), y=2: K4
// (scatter f32), y=3: Q4 plain (16 rows, blocks 0..3 only).
__global__ __launch_bounds__(256) void gemm256_b4(const float* __restrict__ q_emb,
                                                  const float* __restrict__ s_emb,
                                                  const float* __restrict__ know,
                                                  const float* __restrict__ WTq1,
                                                  const float* __restrict__ bq1,
                                                  const float* __restrict__ WTv1,
                                                  const float* __restrict__ bv1,
                                                  const float* __restrict__ WTk4,
                                                  const float* __restrict__ bk4,
                                                  const float* __restrict__ WTq4,
                                                  const float* __restrict__ bq4,
                                                  float* __restrict__ Q1,
                                                  u16* __restrict__ Vtg1,
                                                  float* __restrict__ K4,
                                                  float* __restrict__ Q4) {
    const int mode = blockIdx.y;
    if (mode == 3 && blockIdx.x >= 4) return;
    __shared__ float xs[4][kD];
    const float* X = (mode == 1) ? s_emb : (mode == 3) ? know : q_emb;
    const float* WT = (mode == 0) ? WTq1 : (mode == 1) ? WTv1 : (mode == 2) ? WTk4 : WTq4;
    const float* bias = (mode == 0) ? bq1 : (mode == 1) ? bv1 : (mode == 2) ? bk4 : bq4;
    const int t = threadIdx.x;
    const int r0 = blockIdx.x * 4;

    {
        const int idx = t * 4;
        const int r = idx >> 8, c = idx & 255;
        *(f32x4*)&xs[r][c] = *(const f32x4*)(X + (size_t)(r0 + r) * kD + c);
    }
    __syncthreads();

    const int wv = t >> 6;
    const int c4 = (t & 63) * 4;
    float acc[4];
    {
        f32x4 bv = *(const f32x4*)(bias + c4);
#pragma unroll
        for (int j = 0; j < 4; ++j) acc[j] = bv[j];
    }
    for (int k0 = 0; k0 < kD; k0 += 4) {
        f32x4 w0 = *(const f32x4*)(WT + (size_t)(k0 + 0) * kD + c4);
        f32x4 w1 = *(const f32x4*)(WT + (size_t)(k0 + 1) * kD + c4);
        f32x4 w2 = *(const f32x4*)(WT + (size_t)(k0 + 2) * kD + c4);
        f32x4 w3 = *(const f32x4*)(WT + (size_t)(k0 + 3) * kD + c4);
        f32x4 xv = *(const f32x4*)&xs[wv][k0];
#pragma unroll
        for (int cc = 0; cc < 4; ++cc) {
            acc[cc] = fmaf(xv[0], w0[cc], acc[cc]);
            acc[cc] = fmaf(xv[1], w1[cc], acc[cc]);
            acc[cc] = fmaf(xv[2], w2[cc], acc[cc]);
            acc[cc] = fmaf(xv[3], w3[cc], acc[cc]);
        }
    }
    const int row = r0 + wv;
    if (mode == 3) {
        *(f32x4*)(Q4 + (size_t)row * kD + c4) = *(f32x4*)acc;
    } else if (mode == 1) {
        const int b = row >> 9, s = row & (kS - 1);
        const int h = c4 >> 5, dk = c4 & 31;
        u16* base = Vtg1 + (((size_t)(b * kH + h) * kDK + dk) * kS + s);
#pragma unroll
        for (int j = 0; j < 4; ++j) base[(size_t)j * kS] = f2bf(acc[j]);
    } else {
        float* Y = (mode == 0) ? Q1 : K4;
        const int h = c4 >> 5, dk = c4 & 31;
        *(f32x4*)(Y + (((size_t)(row >> 9) * kH + h) * kS + (row & (kS - 1))) * kDK + dk) =
            *(f32x4*)acc;
    }
}

// Fused epi1 + V4-proj + V-transpose:
// P = LN(q_emb + A1@Wo1^T + bo1)  (LDS only); Vtg = bf16T(P@Wv4^T + bv4)
__global__ __launch_bounds__(256) void epi1v4_kernel(const float* __restrict__ A1,
                                                     const float* __restrict__ qe,
                                                     const float* __restrict__ WTo1,
                                                     const float* __restrict__ bo1,
                                                     const float* __restrict__ lng,
                                                     const float* __restrict__ lnb,
                                                     const float* __restrict__ WTv4,
                                                     const float* __restrict__ bv4,
                                                     u16* __restrict__ Vtg) {
    __shared__ float xs[4][kD];
    __shared__ float ps[4][kD];
    const int t = threadIdx.x;
    const int r0 = blockIdx.x * 4;

    {
        const int chunk = t >> 3;            // 0..31
        const int r = chunk >> 3, h = chunk & 7;
        const int row = r0 + r;
        const float* src = A1 + (((size_t)(row >> 9) * kH + h) * kS + (row & (kS - 1))) * kDK + (t & 7) * 4;
        *(f32x4*)&xs[r][h * kDK + (t & 7) * 4] = *(const f32x4*)src;
    }
    __syncthreads();

    const int wv = t >> 6;
    const int c4 = (t & 63) * 4;
    const int row = r0 + wv;

    {
        float acc[4];
        f32x4 bv = *(const f32x4*)(bo1 + c4);
#pragma unroll
        for (int j = 0; j < 4; ++j) acc[j] = bv[j];
        for (int k0 = 0; k0 < kD; k0 += 4) {
            f32x4 w0 = *(const f32x4*)(WTo1 + (size_t)(k0 + 0) * kD + c4);
            f32x4 w1 = *(const f32x4*)(WTo1 + (size_t)(k0 + 1) * kD + c4);
            f32x4 w2 = *(const f32x4*)(WTo1 + (size_t)(k0 + 2) * kD + c4);
            f32x4 w3 = *(const f32x4*)(WTo1 + (size_t)(k0 + 3) * kD + c4);
            f32x4 xv = *(const f32x4*)&xs[wv][k0];
#pragma unroll
            for (int cc = 0; cc < 4; ++cc) {
                acc[cc] = fmaf(xv[0], w0[cc], acc[cc]);
                acc[cc] = fmaf(xv[1], w1[cc], acc[cc]);
                acc[cc] = fmaf(xv[2], w2[cc], acc[cc]);
                acc[cc] = fmaf(xv[3], w3[cc], acc[cc]);
            }
        }
        f32x4 e = *(const f32x4*)(qe + (size_t)row * kD + c4);
        f32x4 x;
#pragma unroll
        for (int j = 0; j < 4; ++j) x[j] = acc[j] + e[j];
        float s1 = x[0] + x[1] + x[2] + x[3];
        float s2 = x[0] * x[0] + x[1] * x[1] + x[2] * x[2] + x[3] * x[3];
#pragma unroll
        for (int off = 32; off; off >>= 1) {
            s1 += __shfl_xor(s1, off);
            s2 += __shfl_xor(s2, off);
        }
        const float mean = s1 * (1.f / kD);
        const float var = s2 * (1.f / kD) - mean * mean;
        const float rstd = rsqrtf(var + 1e-5f);
        f32x4 g = *(const f32x4*)(lng + c4);
        f32x4 bb = *(const f32x4*)(lnb + c4);
#pragma unroll
        for (int j = 0; j < 4; ++j) ps[wv][c4 + j] = (x[j] - mean) * rstd * g[j] + bb[j];
    }
    __syncthreads();

    {
        float acc[4];
        f32x4 bv = *(const f32x4*)(bv4 + c4);
#pragma unroll
        for (int j = 0; j < 4; ++j) acc[j] = bv[j];
        for (int k0 = 0; k0 < kD; k0 += 4) {
            f32x4 w0 = *(const f32x4*)(WTv4 + (size_t)(k0 + 0) * kD + c4);
            f32x4 w1 = *(const f32x4*)(WTv4 + (size_t)(k0 + 1) * kD + c4);
            f32x4 w2 = *(const f32x4*)(WTv4 + (size_t)(k0 + 2) * kD + c4);
            f32x4 w3 = *(const f32x4*)(WTv4 + (size_t)(k0 + 3) * kD + c4);
            f32x4 xv = *(const f32x4*)&ps[wv][k0];
#pragma unroll
            for (int cc = 0; cc < 4; ++cc) {
                acc[cc] = fmaf(xv[0], w0[cc], acc[cc]);
                acc[cc] = fmaf(xv[1], w1[cc], acc[cc]);
                acc[cc] = fmaf(xv[2], w2[cc], acc[cc]);
                acc[cc] = fmaf(xv[3], w3[cc], acc[cc]);
            }
        }
        const int b = row >> 9, s = row & (kS - 1);
        const int h = c4 >> 5, dk = c4 & 31;
        u16* base = Vtg + (((size_t)(b * kH + h) * kDK + dk) * kS + s);
#pragma unroll
        for (int j = 0; j < 4; ++j) base[(size_t)j * kS] = f2bf(acc[j]);
    }
}

// Unified tiled GEMM (MODE 2 used for epi4: +know+LN+scatter)
template <int RPW, int MODE>
__global__ __launch_bounds__(256) void gemm256(const float* __restrict__ X,
                                               const float* __restrict__ WT,
                                               const float* __restrict__ bias,
                                               const float* __restrict__ extra,
                                               const float* __restrict__ lng,
                                               const float* __restrict__ lnb,
                                               float* __restrict__ Y) {
    constexpr int TM = RPW * 4;
    __shared__ float xs[TM][kD];
    const int t = threadIdx.x;
    const int r0 = blockIdx.x * TM;

    if (MODE == 0) {
#pragma unroll
        for (int it = 0; it < RPW; ++it) {
            const int idx = it * 1024 + t * 4;
            const int r = idx >> 8, c = idx & 255;
            *(f32x4*)&xs[r][c] = *(const f32x4*)(X + (size_t)(r0 + r) * kD + c);
        }
    } else {
#pragma unroll
        for (int it = 0; it < RPW; ++it) {
            const int chunk = it * 32 + (t >> 3);
            const int r = chunk >> 3, h = chunk & 7;
            const int row = r0 + r;
            const float* src = X + (((size_t)(row >> 9) * kH + h) * kS + (row & (kS - 1))) * kDK + (t & 7) * 4;
            *(f32x4*)&xs[r][h * kDK + (t & 7) * 4] = *(const f32x4*)src;
        }
    }
    __syncthreads();

    const int wv = t >> 6;
    const int c4 = (t & 63) * 4;
    float acc[RPW][4];
    {
        f32x4 bv = *(const f32x4*)(bias + c4);
#pragma unroll
        for (int r = 0; r < RPW; ++r)
#pragma unroll
            for (int j = 0; j < 4; ++j) acc[r][j] = bv[j];
    }
    for (int k0 = 0; k0 < kD; k0 += 4) {
        f32x4 w0 = *(const f32x4*)(WT + (size_t)(k0 + 0) * kD + c4);
        f32x4 w1 = *(const f32x4*)(WT + (size_t)(k0 + 1) * kD + c4);
        f32x4 w2 = *(const f32x4*)(WT + (size_t)(k0 + 2) * kD + c4);
        f32x4 w3 = *(const f32x4*)(WT + (size_t)(k0 + 3) * kD + c4);
#pragma unroll
        for (int r = 0; r < RPW; ++r) {
            f32x4 xv = *(const f32x4*)&xs[wv * RPW + r][k0];
#pragma unroll
            for (int cc = 0; cc < 4; ++cc) {
                acc[r][cc] = fmaf(xv[0], w0[cc], acc[r][cc]);
                acc[r][cc] = fmaf(xv[1], w1[cc], acc[r][cc]);
                acc[r][cc] = fmaf(xv[2], w2[cc], acc[r][cc]);
                acc[r][cc] = fmaf(xv[3], w3[cc], acc[r][cc]);
            }
        }
    }

#pragma unroll
    for (int r = 0; r < RPW; ++r) {
        const int row = r0 + wv * RPW + r;
        if (MODE == 0) {
            const int h = c4 >> 5, dk = c4 & 31;
            *(f32x4*)(Y + (((size_t)(row >> 9) * kH + h) * kS + (row & (kS - 1))) * kDK + dk) =
                *(f32x4*)acc[r];
        } else {
            f32x4 x;
            if (MODE == 1) {
                f32x4 e = *(const f32x4*)(extra + (size_t)row * kD + c4);
#pragma unroll
                for (int j = 0; j < 4; ++j) x[j] = acc[r][j] + e[j];
            } else {
                const int nk = (row >> 9) & (kNK - 1);
                f32x4 e = *(const f32x4*)(extra + (size_t)nk * kD + c4);
#pragma unroll
                for (int j = 0; j < 4; ++j) x[j] = acc[r][j] + e[j];
            }
            float s1 = x[0] + x[1] + x[2] + x[3];
            float s2 = x[0] * x[0] + x[1] * x[1] + x[2] * x[2] + x[3] * x[3];
#pragma unroll
            for (int off = 32; off; off >>= 1) {
                s1 += __shfl_xor(s1, off);
                s2 += __shfl_xor(s2, off);
            }
            const float mean = s1 * (1.f / kD);
            const float var = s2 * (1.f / kD) - mean * mean;
            const float rstd = rsqrtf(var + 1e-5f);
            f32x4 g = *(const f32x4*)(lng + c4);
            f32x4 bb = *(const f32x4*)(lnb + c4);
            f32x4 y;
#pragma unroll
            for (int j = 0; j < 4; ++j) y[j] = (x[j] - mean) * rstd * g[j] + bb[j];
            if (MODE == 1) {
                *(f32x4*)(Y + (size_t)row * kD + c4) = y;
            } else {
                const int bnk = row >> 9, s = row & (kS - 1);
                const int nk = bnk & (kNK - 1), b = bnk >> 4;
                nt_store4(Y + (((size_t)(b * kS + s) * kNK + nk) * kD) + c4, y);
            }
        }
    }
}

// Fused: blocks [0,512): block-1 attention (16 q rows each);
//        blocks [512,576): block-4 prep, 4 panels/block (one per wave).
__global__ __launch_bounds__(256) void attn1_prep_kernel(const float* __restrict__ Q1,
                                                         const u16* __restrict__ Vtg1,
                                                         const float* __restrict__ gam,
                                                         const float* __restrict__ Q4,
                                                         const float* __restrict__ K4,
                                                         float* __restrict__ rawP,
                                                         float* __restrict__ CpreP,
                                                         float* __restrict__ q_scores,
                                                         float* __restrict__ A1) {
    extern __shared__ char smem[];
    const int bx = blockIdx.x;
    const int tid = threadIdx.x;
    const int lane = tid & 63;
    const int w = tid >> 6;

    if (bx >= kB * kH * (kS / 16)) {
        // ---- attn4_prep path: panel = (bx-512)*4 + w ----
        const int panel = (bx - kB * kH * (kS / 16)) * 4 + w;
        const int h = panel & (kH - 1);
        const int bnk = panel >> 3;
        const int nk = bnk & (kNK - 1);
        const int b = bnk >> 4;
        const float* Kp = K4 + (size_t)(b * kH + h) * kS * kDK;
        float qv[kDK];
        const float* Qr = Q4 + (size_t)nk * kD + h * kDK;
#pragma unroll
        for (int d = 0; d < kDK; ++d) qv[d] = Qr[d];

        const int k0 = lane * 8;
        float raw[8];
        float m = -3e38f;
#pragma unroll
        for (int j = 0; j < 8; ++j) {
            const float* kr = Kp + (size_t)(k0 + j) * kDK;
            float s = 0.f;
#pragma unroll
            for (int d4 = 0; d4 < 8; ++d4) {
                f32x4 kv = *(const f32x4*)(kr + d4 * 4);
                s = fmaf(qv[d4 * 4 + 0], kv[0], s);
                s = fmaf(qv[d4 * 4 + 1], kv[1], s);
                s = fmaf(qv[d4 * 4 + 2], kv[2], s);
                s = fmaf(qv[d4 * 4 + 3], kv[3], s);
            }
            raw[j] = s * kScale;
            m = fmaxf(m, raw[j]);
        }
        m = wave_max64(m);
        float E[8];
        float s = 0.f;
#pragma unroll
        for (int j = 0; j < 8; ++j) { E[j] = __expf(raw[j] - m); s += E[j]; }
        float inc = s;
#pragma unroll
        for (int off = 1; off < 64; off <<= 1) {
            float t2 = __shfl_up(inc, off);
            if (lane >= off) inc += t2;
        }
        float run = inc - s;
        float cp[8];
#pragma unroll
        for (int j = 0; j < 8; ++j) { run += E[j]; cp[j] = run; }

        float* rrow = rawP + (size_t)panel * kS + k0;
        float* crow = CpreP + (size_t)panel * kS + k0;
        *(f32x4*)(rrow) = *(f32x4*)(raw);
        *(f32x4*)(rrow + 4) = *(f32x4*)(raw + 4);
        *(f32x4*)(crow) = *(f32x4*)(cp);
        *(f32x4*)(crow + 4) = *(f32x4*)(cp + 4);
        return;
    }

    // ---- attn1 path ----
    float* Sl = (float*)smem;        // [16][kSL] f32 = 33792 B
    u16* Pl = (u16*)smem;            // aliases Sl after barrier

    const int bh = bx >> 5;                  // kS/16 = 32 chunks
    const int q0 = (bx & 31) * 16;
    const int h = bh & (kH - 1);
    const float* Kb = Q1 + (size_t)bh * kS * kDK;   // K == Q

    {
        const int qrow = q0 + (lane & 15);
        const int dof = (lane >> 4) * 8;
        f32x4 qa = *(const f32x4*)(Kb + (size_t)qrow * kDK + dof);
        f32x4 qb = *(const f32x4*)(Kb + (size_t)qrow * kDK + dof + 4);
        s16x8 aq_h, aq_l;
#pragma unroll
        for (int j = 0; j < 4; ++j) {
            float f = qa[j];
            u16 hi = f2bf(f);
            aq_h[j] = (short)hi;
            aq_l[j] = (short)f2bf(f - bf2f(hi));
            f = qb[j];
            hi = f2bf(f);
            aq_h[4 + j] = (short)hi;
            aq_l[4 + j] = (short)f2bf(f - bf2f(hi));
        }
        for (int kt = w * 8; kt < w * 8 + 8; ++kt) {
            const int krow = kt * 16 + (lane & 15);
            f32x4 ka = *(const f32x4*)(Kb + (size_t)krow * kDK + dof);
            f32x4 kb2 = *(const f32x4*)(Kb + (size_t)krow * kDK + dof + 4);
            s16x8 bk_h, bk_l;
#pragma unroll
            for (int j = 0; j < 4; ++j) {
                float f = ka[j];
                u16 hi = f2bf(f);
                bk_h[j] = (short)hi;
                bk_l[j] = (short)f2bf(f - bf2f(hi));
                f = kb2[j];
                hi = f2bf(f);
                bk_h[4 + j] = (short)hi;
                bk_l[4 + j] = (short)f2bf(f - bf2f(hi));
            }
            f32x4 acc = {0.f, 0.f, 0.f, 0.f};
            acc = __builtin_amdgcn_mfma_f32_16x16x32_bf16(aq_h, bk_h, acc, 0, 0, 0);
            acc = __builtin_amdgcn_mfma_f32_16x16x32_bf16(aq_l, bk_h, acc, 0, 0, 0);
            acc = __builtin_amdgcn_mfma_f32_16x16x32_bf16(aq_h, bk_l, acc, 0, 0, 0);
            const int colk = kt * 16 + (lane & 15);
            const int seg = colk >> 5, ii = colk & 31;
#pragma unroll
            for (int j = 0; j < 4; ++j) {
                const int row = (lane >> 4) * 4 + j;
                Sl[row * kSL + seg * 33 + ii] = acc[j] * kScale;
            }
        }
    }
    __syncthreads();

    const float gh = -fabsf(gam[h]);
    const int r = tid >> 4, seg16 = tid & 15;
    const int q = q0 + r, L = q + 1, ks = seg16 * 32;
    float sv[32];
    {
        const float* srow = Sl + r * kSL + seg16 * 33;
#pragma unroll
        for (int i = 0; i < 32; ++i) sv[i] = srow[i];
    }
    __syncthreads();
    {
        const int nv = min(max(L - ks, 0), 32);
        float m = -3e38f;
#pragma unroll
        for (int i = 0; i < 32; ++i)
            if (i < nv) m = fmaxf(m, sv[i]);
#pragma unroll
        for (int off = 1; off < 16; off <<= 1) m = fmaxf(m, __shfl_xor(m, off));
        float segsum = 0.f;
#pragma unroll
        for (int i = 0; i < 32; ++i)
            if (i < nv) segsum += __expf(sv[i] - m);
        float tot = segsum;
#pragma unroll
        for (int off = 1; off < 16; off <<= 1) tot += __shfl_xor(tot, off);
        float inc = segsum;
#pragma unroll
        for (int off = 1; off < 16; off <<= 1) {
            const float tmp = __shfl_up(inc, off);
            if ((tid & 15) >= off) inc += tmp;
        }
        float run = inc - segsum;
        const float inv_tot = 1.f / tot;
        float m2 = -3e38f;
#pragma unroll
        for (int i = 0; i < 32; ++i) {
            if (i < nv) {
                const float E = __expf(sv[i] - m);
                run += E;
                const float rem = 1.f - run * inv_tot;
                const float pos = (float)(q - (ks + i));
                const float val = fmaxf(rem * pos, 0.f);
                const float te = fmaxf(__expf(gh * sqrtf(val)), 1e-5f);
                const float s2 = sv[i] * te;
                sv[i] = s2;
                m2 = fmaxf(m2, s2);
            }
        }
#pragma unroll
        for (int off = 1; off < 16; off <<= 1) m2 = fmaxf(m2, __shfl_xor(m2, off));
        float sum2 = 0.f;
#pragma unroll
        for (int i = 0; i < 32; ++i) {
            const float p = (i < nv) ? __expf(sv[i] - m2) : 0.f;
            sv[i] = p;
            sum2 += p;
        }
#pragma unroll
        for (int off = 1; off < 16; off <<= 1) sum2 += __shfl_xor(sum2, off);
        const float inv2 = 1.f / sum2;
        float* qrow = q_scores + ((size_t)bh * kS + q) * kS + ks;
        u16* prow = Pl + r * kPS + ks;
#pragma unroll
        for (int i = 0; i < 32; i += 4) {
            f32x4 o;
            u16x4 pb;
#pragma unroll
            for (int j = 0; j < 4; ++j) {
                const float p = sv[i + j] * inv2;
                o[j] = p;
                pb[j] = f2bf(p);
            }
            nt_store4(qrow + i, o);
            *(u16x4*)(prow + i) = pb;
        }
    }
    __syncthreads();

    if (w < 2) {
        const int dt = w;
        const u16* Arow = Pl + (size_t)(lane & 15) * kPS + (lane >> 4) * 8;
        const u16* Brow = Vtg1 + ((size_t)bh * kDK + dt * 16 + (lane & 15)) * kS + (lane >> 4) * 8;
        f32x4 acc = {0.f, 0.f, 0.f, 0.f};
#pragma unroll
        for (int kc = 0; kc < kS; kc += 32) {
            s16x8 a = *(const s16x8*)(Arow + kc);
            s16x8 b = *(const s16x8*)(Brow + kc);
            acc = __builtin_amdgcn_mfma_f32_16x16x32_bf16(a, b, acc, 0, 0, 0);
        }
        const int d = dt * 16 + (lane & 15);
#pragma unroll
        for (int j = 0; j < 4; ++j) {
            const int row = (lane >> 4) * 4 + j;
            A1[((size_t)bh * kS + (q0 + row)) * kDK + d] = acc[j];
        }
    }
}

// Block-4 main v5: fused single-pass softmax; nt k_scores stores; PV B from global Vtg
__global__ __launch_bounds__(256) void attn4_main(const float* __restrict__ rawP,
                                                  const float* __restrict__ CpreP,
                                                  const u16* __restrict__ Vtg,
                                                  const float* __restrict__ gam,
                                                  float* __restrict__ k_scores,
                                                  float* __restrict__ A4) {
    extern __shared__ char smem[];
    u16* Pl = (u16*)smem;                           // [32][kPS] bf16
    float* raws_l = (float*)(smem + 32 * kPS * 2);  // [512]
    float* cps_l = raws_l + kS;                     // [512]

    const int panel = blockIdx.x;
    const int q0 = blockIdx.y * 32;
    const int h = panel & (kH - 1);
    const int bnk = panel >> 3;
    const int nk = bnk & (kNK - 1);
    const int b = bnk >> 4;
    const int tid = threadIdx.x;
    const int lane = tid & 63;
    const int w = tid >> 6;

    for (int i = tid; i < kS; i += 256) {
        raws_l[i] = rawP[(size_t)panel * kS + i];
        cps_l[i] = CpreP[(size_t)panel * kS + i];
    }
    __syncthreads();

    const float gh = -fabsf(gam[h]);
    const int rbase = w * 8;
    const int k0 = lane * 8;
    float rw[8], cp[8];
    *(f32x4*)(rw) = *(const f32x4*)(raws_l + k0);
    *(f32x4*)(rw + 4) = *(const f32x4*)(raws_l + k0 + 4);
    *(f32x4*)(cp) = *(const f32x4*)(cps_l + k0);
    *(f32x4*)(cp + 4) = *(const f32x4*)(cps_l + k0 + 4);

    for (int r = 0; r < 8; ++r) {
        const int row = rbase + r;
        const int Lr = q0 + row;
        float* krow = k_scores + ((size_t)((b * kH + h) * kS + Lr) * kNK + nk) * kS;
        u16* prow = Pl + (size_t)row * kPS + k0;
        if (Lr == 0) {
            f32x4 z = {0.f, 0.f, 0.f, 0.f};
            nt_store4(krow + k0, z);
            nt_store4(krow + k0 + 4, z);
            u16x8 zb = {0, 0, 0, 0, 0, 0, 0, 0};
            *(u16x8*)(prow) = zb;
            continue;
        }
        const float invCL = 1.f / cps_l[Lr - 1];
        const float fL = (float)(Lr - k0);
        float s2v[8];
        float mloc = -3e38f;
#pragma unroll
        for (int j = 0; j < 8; ++j) {
            const float rem = 1.f - cp[j] * invCL;
            const float val = fmaxf(rem * (fL - (float)j), 0.f);
            const float te = fmaxf(__expf(gh * sqrtf(val)), 1e-5f);
            const float s2 = rw[j] * te;
            s2v[j] = s2;
            if (k0 + j < Lr) mloc = fmaxf(mloc, s2);
        }
        const float m2 = wave_max64(mloc);
        float p[8];
        float psum = 0.f;
#pragma unroll
        for (int j = 0; j < 8; ++j) {
            p[j] = (k0 + j < Lr) ? __expf(s2v[j] - m2) : 0.f;
            psum += p[j];
        }
        const float sum2 = wave_sum64(psum);
        const float scl = fminf(sum2, 5.f) / sum2;
        u16x8 pb;
#pragma unroll
        for (int j = 0; j < 8; ++j) {
            p[j] *= scl;
            pb[j] = f2bf(p[j]);
        }
        nt_store4(krow + k0, *(f32x4*)(p));
        nt_store4(krow + k0 + 4, *(f32x4*)(p + 4));
        *(u16x8*)(prow) = pb;
    }
    __syncthreads();

    const int rowblk = (w & 1) * 16;
    const int dblk = (w >> 1) * 16;
    const u16* Arow = Pl + (size_t)(rowblk + (lane & 15)) * kPS + (lane >> 4) * 8;
    const u16* Brow = Vtg + ((size_t)(b * kH + h) * kDK + dblk + (lane & 15)) * kS + (lane >> 4) * 8;
    f32x4 acc = {0.f, 0.f, 0.f, 0.f};
#pragma unroll
    for (int kc = 0; kc < kS; kc += 32) {
        s16x8 a = *(const s16x8*)(Arow + kc);
        s16x8 bfr = *(const s16x8*)(Brow + kc);
        acc = __builtin_amdgcn_mfma_f32_16x16x32_bf16(a, bfr, acc, 0, 0, 0);
    }
    const int d = dblk + (lane & 15);
#pragma unroll
    for (int j = 0; j < 4; ++j) {
        const int row = rowblk + (lane >> 4) * 4 + j;
        A4[((size_t)panel * kS + (q0 + row)) * kDK + d] = acc[j];
    }
}

extern "C" void kernel_launch(void* const* d_in, const int* in_sizes, int n_in,
                              void* d_out, int out_size, void* d_ws, size_t ws_size,
                              hipStream_t stream) {
    (void)in_sizes; (void)n_in; (void)out_size; (void)ws_size;

    const float* q_emb = (const float*)d_in[0];
    const float* s_emb = (const float*)d_in[1];
    const float* Wq1 = (const float*)d_in[5];  const float* bq1 = (const float*)d_in[6];
    const float* Wv1 = (const float*)d_in[7];  const float* bv1 = (const float*)d_in[8];
    const float* Wo1 = (const float*)d_in[9];  const float* bo1 = (const float*)d_in[10];
    const float* gam1 = (const float*)d_in[11];
    const float* ln1g = (const float*)d_in[12]; const float* ln1b = (const float*)d_in[13];
    const float* Wq4 = (const float*)d_in[14]; const float* bq4 = (const float*)d_in[15];
    const float* Wk4 = (const float*)d_in[16]; const float* bk4 = (const float*)d_in[17];
    const float* Wv4 = (const float*)d_in[18]; const float* bv4 = (const float*)d_in[19];
    const float* Wo4 = (const float*)d_in[20]; const float* bo4 = (const float*)d_in[21];
    const float* gam4 = (const float*)d_in[22];
    const float* ln4g = (const float*)d_in[23]; const float* ln4b = (const float*)d_in[24];
    const float* know = (const float*)d_in[25];

    float* ws = (float*)d_ws;
    const size_t NBHSD = (size_t)kB * kH * kS * kDK;       // 262144
    float* Q1 = ws;
    float* RAW = Q1 + NBHSD;                                // rawP+CpreP = 262144 floats
    float* A1 = RAW + NBHSD;
    float* K4 = A1 + NBHSD;
    float* Q4 = K4 + NBHSD;                                 // NK*D = 4096
    float* A4 = Q4 + (size_t)kNK * kD;                      // 4194304
    float* WT = A4 + (size_t)kB * kNK * kH * kS * kDK;      // 7 * 65536 floats
    u16* Vtg = (u16*)(WT + 7 * (size_t)kD * kD);            // 262144 u16
    u16* Vtg1 = Vtg + (size_t)kB * kH * kDK * kS;           // 262144 u16

    float* rawP = RAW;                                      // 131072 floats
    float* CpreP = RAW + (size_t)kB * kNK * kH * kS;        // +131072

    float* WTq1 = WT + 0 * (size_t)kD * kD;
    float* WTv1 = WT + 1 * (size_t)kD * kD;
    float* WTo1 = WT + 2 * (size_t)kD * kD;
    float* WTk4 = WT + 3 * (size_t)kD * kD;
    float* WTv4 = WT + 4 * (size_t)kD * kD;
    float* WTo4 = WT + 5 * (size_t)kD * kD;
    float* WTq4 = WT + 6 * (size_t)kD * kD;

    float* zout = (float*)d_out;
    float* q_scores = zout + (size_t)kB * kS * kNK * kD;
    float* k_scores = q_scores + (size_t)kB * kH * kS * kS;

    // 1. weight transposes (7 matrices)
    {
        dim3 g(64, 7);
        wt_kernel<<<g, 256, 0, stream>>>(Wq1, Wv1, Wo1, Wk4, Wv4, Wo4, Wq4, WT);
    }
    // 2. batched projections: Q1, Vtg1(bf16T), K4, Q4
    {
        dim3 g(kB * kS / 4, 4);
        gemm256_b4<<<g, 256, 0, stream>>>(q_emb, s_emb, know,
                                          WTq1, bq1, WTv1, bv1, WTk4, bk4, WTq4, bq4,
                                          Q1, Vtg1, K4, Q4);
    }
    // 3. fused block-1 attention + block-4 prep
    {
        const int nb1 = kB * kH * (kS / 16);                // 512
        const int nbp = kB * kNK * kH / 4;                  // 64
        const int lds1 = 16 * kSL * 4;                      // 33792
        attn1_prep_kernel<<<nb1 + nbp, 256, lds1, stream>>>(Q1, Vtg1, gam1, Q4, K4,
                                                            rawP, CpreP, q_scores, A1);
    }
    // 4. fused epi1 + V4 proj + V transpose -> Vtg
    epi1v4_kernel<<<kB * kS / 4, 256, 0, stream>>>(A1, q_emb, WTo1, bo1, ln1g, ln1b,
                                                   WTv4, bv4, Vtg);
    // 5. block-4 attention
    {
        dim3 g5(kB * kNK * kH, kS / 32);
        const int lds_bytes = 32 * kPS * 2 + 2 * kS * 4;    // 37376
        attn4_main<<<g5, 256, lds_bytes, stream>>>(rawP, CpreP, Vtg, gam4, k_scores, A4);
    }
    // 6. block-4 epilogue
    gemm256<4, 2><<<kB * kNK * kS / 16, 256, 0, stream>>>(A4, WTo4, bo4, know, ln4g, ln4b, zout);
}

// Round 13
// 215.596 us; speedup vs baseline: 1.0945x; 1.0945x over previous
//
#include <hip/hip_runtime.h>

// DTransformer forward (f32 in/out, f32 internal)
// B=2 S=512 D=256 H=8 DK=32 NK=16

namespace {
constexpr int kB = 2, kS = 512, kD = 256, kH = 8, kDK = 32, kNK = 16;
constexpr float kScale = 0.17677669529663687f;  // 1/sqrt(32)
constexpr int kPS = 520;                        // Pl row stride (bf16 elems)
constexpr int kSL = 528;                        // Sl row stride (f32): 16 segs x 33
}

typedef unsigned short u16;
typedef u16 u16x4 __attribute__((ext_vector_type(4)));
typedef u16 u16x8 __attribute__((ext_vector_type(8)));
typedef short s16x8 __attribute__((ext_vector_type(8)));
typedef float f32x4 __attribute__((ext_vector_type(4)));

__device__ __forceinline__ float bf2f(u16 u) { return __uint_as_float(((unsigned)u) << 16); }
__device__ __forceinline__ u16 f2bf(float f) {
    unsigned u = __float_as_uint(f);
    return (u16)((u + 0x7fffu + ((u >> 16) & 1u)) >> 16);
}

__device__ __forceinline__ float wave_max64(float v) {
#pragma unroll
    for (int off = 32; off; off >>= 1) v = fmaxf(v, __shfl_xor(v, off));
    return v;
}
__device__ __forceinline__ float wave_sum64(float v) {
#pragma unroll
    for (int off = 32; off; off >>= 1) v += __shfl_xor(v, off);
    return v;
}

// Tiled transpose of 7 weight matrices [c][k] -> [k][c] (256x256 each), coalesced.
__global__ __launch_bounds__(256) void wt_kernel(const float* __restrict__ W0,
                                                 const float* __restrict__ W1,
                                                 const float* __restrict__ W2,
                                                 const float* __restrict__ W3,
                                                 const float* __restrict__ W4,
                                                 const float* __restrict__ W5,
                                                 const float* __restrict__ W6,
                                                 float* __restrict__ WT) {
    __shared__ float tile[32][33];
    const float* srcs[7] = {W0, W1, W2, W3, W4, W5, W6};
    const float* W = srcs[blockIdx.y];
    float* T = WT + (size_t)blockIdx.y * kD * kD;
    const int tx = blockIdx.x & 7, ty = blockIdx.x >> 3;
    const int t = threadIdx.x;
    {
        const int cl = t >> 3, kl = (t & 7) * 4;
        f32x4 v = *(const f32x4*)(W + (size_t)(ty * 32 + cl) * kD + tx * 32 + kl);
        tile[cl][kl] = v[0]; tile[cl][kl + 1] = v[1];
        tile[cl][kl + 2] = v[2]; tile[cl][kl + 3] = v[3];
    }
    __syncthreads();
    {
        const int kl = t >> 3, cl = (t & 7) * 4;
        f32x4 o = {tile[cl][kl], tile[cl + 1][kl], tile[cl + 2][kl], tile[cl + 3][kl]};
        *(f32x4*)(T + (size_t)(tx * 32 + kl) * kD + ty * 32 + cl) = o;
    }
}

// Batched projections: y=0: Q1 (scatter f32), y=1: Vtg1 (bf16 transposed), y=2: K4
// (scatter f32), y=3: Q4 plain (16 rows, blocks 0..3 only).
__global__ __launch_bounds__(256) void gemm256_b4(const float* __restrict__ q_emb,
                                                  const float* __restrict__ s_emb,
                                                  const float* __restrict__ know,
                                                  const float* __restrict__ WTq1,
                                                  const float* __restrict__ bq1,
                                                  const float* __restrict__ WTv1,
                                                  const float* __restrict__ bv1,
                                                  const float* __restrict__ WTk4,
                                                  const float* __restrict__ bk4,
                                                  const float* __restrict__ WTq4,
                                                  const float* __restrict__ bq4,
                                                  float* __restrict__ Q1,
                                                  u16* __restrict__ Vtg1,
                                                  float* __restrict__ K4,
                                                  float* __restrict__ Q4) {
    const int mode = blockIdx.y;
    if (mode == 3 && blockIdx.x >= 4) return;
    __shared__ float xs[4][kD];
    const float* X = (mode == 1) ? s_emb : (mode == 3) ? know : q_emb;
    const float* WT = (mode == 0) ? WTq1 : (mode == 1) ? WTv1 : (mode == 2) ? WTk4 : WTq4;
    const float* bias = (mode == 0) ? bq1 : (mode == 1) ? bv1 : (mode == 2) ? bk4 : bq4;
    const int t = threadIdx.x;
    const int r0 = blockIdx.x * 4;

    {
        const int idx = t * 4;
        const int r = idx >> 8, c = idx & 255;
        *(f32x4*)&xs[r][c] = *(const f32x4*)(X + (size_t)(r0 + r) * kD + c);
    }
    __syncthreads();

    const int wv = t >> 6;
    const int c4 = (t & 63) * 4;
    float acc[4];
    {
        f32x4 bv = *(const f32x4*)(bias + c4);
#pragma unroll
        for (int j = 0; j < 4; ++j) acc[j] = bv[j];
    }
    for (int k0 = 0; k0 < kD; k0 += 4) {
        f32x4 w0 = *(const f32x4*)(WT + (size_t)(k0 + 0) * kD + c4);
        f32x4 w1 = *(const f32x4*)(WT + (size_t)(k0 + 1) * kD + c4);
        f32x4 w2 = *(const f32x4*)(WT + (size_t)(k0 + 2) * kD + c4);
        f32x4 w3 = *(const f32x4*)(WT + (size_t)(k0 + 3) * kD + c4);
        f32x4 xv = *(const f32x4*)&xs[wv][k0];
#pragma unroll
        for (int cc = 0; cc < 4; ++cc) {
            acc[cc] = fmaf(xv[0], w0[cc], acc[cc]);
            acc[cc] = fmaf(xv[1], w1[cc], acc[cc]);
            acc[cc] = fmaf(xv[2], w2[cc], acc[cc]);
            acc[cc] = fmaf(xv[3], w3[cc], acc[cc]);
        }
    }
    const int row = r0 + wv;
    if (mode == 3) {
        *(f32x4*)(Q4 + (size_t)row * kD + c4) = *(f32x4*)acc;
    } else if (mode == 1) {
        const int b = row >> 9, s = row & (kS - 1);
        const int h = c4 >> 5, dk = c4 & 31;
        u16* base = Vtg1 + (((size_t)(b * kH + h) * kDK + dk) * kS + s);
#pragma unroll
        for (int j = 0; j < 4; ++j) base[(size_t)j * kS] = f2bf(acc[j]);
    } else {
        float* Y = (mode == 0) ? Q1 : K4;
        const int h = c4 >> 5, dk = c4 & 31;
        *(f32x4*)(Y + (((size_t)(row >> 9) * kH + h) * kS + (row & (kS - 1))) * kDK + dk) =
            *(f32x4*)acc;
    }
}

// Fused epi1 + V4-proj + V-transpose:
// P = LN(q_emb + A1@Wo1^T + bo1)  (LDS only); Vtg = bf16T(P@Wv4^T + bv4)
__global__ __launch_bounds__(256) void epi1v4_kernel(const float* __restrict__ A1,
                                                     const float* __restrict__ qe,
                                                     const float* __restrict__ WTo1,
                                                     const float* __restrict__ bo1,
                                                     const float* __restrict__ lng,
                                                     const float* __restrict__ lnb,
                                                     const float* __restrict__ WTv4,
                                                     const float* __restrict__ bv4,
                                                     u16* __restrict__ Vtg) {
    __shared__ float xs[4][kD];
    __shared__ float ps[4][kD];
    const int t = threadIdx.x;
    const int r0 = blockIdx.x * 4;

    {
        const int chunk = t >> 3;            // 0..31
        const int r = chunk >> 3, h = chunk & 7;
        const int row = r0 + r;
        const float* src = A1 + (((size_t)(row >> 9) * kH + h) * kS + (row & (kS - 1))) * kDK + (t & 7) * 4;
        *(f32x4*)&xs[r][h * kDK + (t & 7) * 4] = *(const f32x4*)src;
    }
    __syncthreads();

    const int wv = t >> 6;
    const int c4 = (t & 63) * 4;
    const int row = r0 + wv;

    {
        float acc[4];
        f32x4 bv = *(const f32x4*)(bo1 + c4);
#pragma unroll
        for (int j = 0; j < 4; ++j) acc[j] = bv[j];
        for (int k0 = 0; k0 < kD; k0 += 4) {
            f32x4 w0 = *(const f32x4*)(WTo1 + (size_t)(k0 + 0) * kD + c4);
            f32x4 w1 = *(const f32x4*)(WTo1 + (size_t)(k0 + 1) * kD + c4);
            f32x4 w2 = *(const f32x4*)(WTo1 + (size_t)(k0 + 2) * kD + c4);
            f32x4 w3 = *(const f32x4*)(WTo1 + (size_t)(k0 + 3) * kD + c4);
            f32x4 xv = *(const f32x4*)&xs[wv][k0];
#pragma unroll
            for (int cc = 0; cc < 4; ++cc) {
                acc[cc] = fmaf(xv[0], w0[cc], acc[cc]);
                acc[cc] = fmaf(xv[1], w1[cc], acc[cc]);
                acc[cc] = fmaf(xv[2], w2[cc], acc[cc]);
                acc[cc] = fmaf(xv[3], w3[cc], acc[cc]);
            }
        }
        f32x4 e = *(const f32x4*)(qe + (size_t)row * kD + c4);
        f32x4 x;
#pragma unroll
        for (int j = 0; j < 4; ++j) x[j] = acc[j] + e[j];
        float s1 = x[0] + x[1] + x[2] + x[3];
        float s2 = x[0] * x[0] + x[1] * x[1] + x[2] * x[2] + x[3] * x[3];
#pragma unroll
        for (int off = 32; off; off >>= 1) {
            s1 += __shfl_xor(s1, off);
            s2 += __shfl_xor(s2, off);
        }
        const float mean = s1 * (1.f / kD);
        const float var = s2 * (1.f / kD) - mean * mean;
        const float rstd = rsqrtf(var + 1e-5f);
        f32x4 g = *(const f32x4*)(lng + c4);
        f32x4 bb = *(const f32x4*)(lnb + c4);
#pragma unroll
        for (int j = 0; j < 4; ++j) ps[wv][c4 + j] = (x[j] - mean) * rstd * g[j] + bb[j];
    }
    __syncthreads();

    {
        float acc[4];
        f32x4 bv = *(const f32x4*)(bv4 + c4);
#pragma unroll
        for (int j = 0; j < 4; ++j) acc[j] = bv[j];
        for (int k0 = 0; k0 < kD; k0 += 4) {
            f32x4 w0 = *(const f32x4*)(WTv4 + (size_t)(k0 + 0) * kD + c4);
            f32x4 w1 = *(const f32x4*)(WTv4 + (size_t)(k0 + 1) * kD + c4);
            f32x4 w2 = *(const f32x4*)(WTv4 + (size_t)(k0 + 2) * kD + c4);
            f32x4 w3 = *(const f32x4*)(WTv4 + (size_t)(k0 + 3) * kD + c4);
            f32x4 xv = *(const f32x4*)&ps[wv][k0];
#pragma unroll
            for (int cc = 0; cc < 4; ++cc) {
                acc[cc] = fmaf(xv[0], w0[cc], acc[cc]);
                acc[cc] = fmaf(xv[1], w1[cc], acc[cc]);
                acc[cc] = fmaf(xv[2], w2[cc], acc[cc]);
                acc[cc] = fmaf(xv[3], w3[cc], acc[cc]);
            }
        }
        const int b = row >> 9, s = row & (kS - 1);
        const int h = c4 >> 5, dk = c4 & 31;
        u16* base = Vtg + (((size_t)(b * kH + h) * kDK + dk) * kS + s);
#pragma unroll
        for (int j = 0; j < 4; ++j) base[(size_t)j * kS] = f2bf(acc[j]);
    }
}

// Unified tiled GEMM (MODE 2 used for epi4: +know+LN+scatter)
template <int RPW, int MODE>
__global__ __launch_bounds__(256) void gemm256(const float* __restrict__ X,
                                               const float* __restrict__ WT,
                                               const float* __restrict__ bias,
                                               const float* __restrict__ extra,
                                               const float* __restrict__ lng,
                                               const float* __restrict__ lnb,
                                               float* __restrict__ Y) {
    constexpr int TM = RPW * 4;
    __shared__ float xs[TM][kD];
    const int t = threadIdx.x;
    const int r0 = blockIdx.x * TM;

    if (MODE == 0) {
#pragma unroll
        for (int it = 0; it < RPW; ++it) {
            const int idx = it * 1024 + t * 4;
            const int r = idx >> 8, c = idx & 255;
            *(f32x4*)&xs[r][c] = *(const f32x4*)(X + (size_t)(r0 + r) * kD + c);
        }
    } else {
#pragma unroll
        for (int it = 0; it < RPW; ++it) {
            const int chunk = it * 32 + (t >> 3);
            const int r = chunk >> 3, h = chunk & 7;
            const int row = r0 + r;
            const float* src = X + (((size_t)(row >> 9) * kH + h) * kS + (row & (kS - 1))) * kDK + (t & 7) * 4;
            *(f32x4*)&xs[r][h * kDK + (t & 7) * 4] = *(const f32x4*)src;
        }
    }
    __syncthreads();

    const int wv = t >> 6;
    const int c4 = (t & 63) * 4;
    float acc[RPW][4];
    {
        f32x4 bv = *(const f32x4*)(bias + c4);
#pragma unroll
        for (int r = 0; r < RPW; ++r)
#pragma unroll
            for (int j = 0; j < 4; ++j) acc[r][j] = bv[j];
    }
    for (int k0 = 0; k0 < kD; k0 += 4) {
        f32x4 w0 = *(const f32x4*)(WT + (size_t)(k0 + 0) * kD + c4);
        f32x4 w1 = *(const f32x4*)(WT + (size_t)(k0 + 1) * kD + c4);
        f32x4 w2 = *(const f32x4*)(WT + (size_t)(k0 + 2) * kD + c4);
        f32x4 w3 = *(const f32x4*)(WT + (size_t)(k0 + 3) * kD + c4);
#pragma unroll
        for (int r = 0; r < RPW; ++r) {
            f32x4 xv = *(const f32x4*)&xs[wv * RPW + r][k0];
#pragma unroll
            for (int cc = 0; cc < 4; ++cc) {
                acc[r][cc] = fmaf(xv[0], w0[cc], acc[r][cc]);
                acc[r][cc] = fmaf(xv[1], w1[cc], acc[r][cc]);
                acc[r][cc] = fmaf(xv[2], w2[cc], acc[r][cc]);
                acc[r][cc] = fmaf(xv[3], w3[cc], acc[r][cc]);
            }
        }
    }

#pragma unroll
    for (int r = 0; r < RPW; ++r) {
        const int row = r0 + wv * RPW + r;
        if (MODE == 0) {
            const int h = c4 >> 5, dk = c4 & 31;
            *(f32x4*)(Y + (((size_t)(row >> 9) * kH + h) * kS + (row & (kS - 1))) * kDK + dk) =
                *(f32x4*)acc[r];
        } else {
            f32x4 x;
            if (MODE == 1) {
                f32x4 e = *(const f32x4*)(extra + (size_t)row * kD + c4);
#pragma unroll
                for (int j = 0; j < 4; ++j) x[j] = acc[r][j] + e[j];
            } else {
                const int nk = (row >> 9) & (kNK - 1);
                f32x4 e = *(const f32x4*)(extra + (size_t)nk * kD + c4);
#pragma unroll
                for (int j = 0; j < 4; ++j) x[j] = acc[r][j] + e[j];
            }
            float s1 = x[0] + x[1] + x[2] + x[3];
            float s2 = x[0] * x[0] + x[1] * x[1] + x[2] * x[2] + x[3] * x[3];
#pragma unroll
            for (int off = 32; off; off >>= 1) {
                s1 += __shfl_xor(s1, off);
                s2 += __shfl_xor(s2, off);
            }
            const float mean = s1 * (1.f / kD);
            const float var = s2 * (1.f / kD) - mean * mean;
            const float rstd = rsqrtf(var + 1e-5f);
            f32x4 g = *(const f32x4*)(lng + c4);
            f32x4 bb = *(const f32x4*)(lnb + c4);
            f32x4 y;
#pragma unroll
            for (int j = 0; j < 4; ++j) y[j] = (x[j] - mean) * rstd * g[j] + bb[j];
            if (MODE == 1) {
                *(f32x4*)(Y + (size_t)row * kD + c4) = y;
            } else {
                const int bnk = row >> 9, s = row & (kS - 1);
                const int nk = bnk & (kNK - 1), b = bnk >> 4;
                *(f32x4*)(Y + (((size_t)(b * kS + s) * kNK + nk) * kD) + c4) = y;
            }
        }
    }
}

// Fused: blocks [0,512): block-1 attention (16 q rows each);
//        blocks [512,576): block-4 prep, 4 panels/block (one per wave).
__global__ __launch_bounds__(256) void attn1_prep_kernel(const float* __restrict__ Q1,
                                                         const u16* __restrict__ Vtg1,
                                                         const float* __restrict__ gam,
                                                         const float* __restrict__ Q4,
                                                         const float* __restrict__ K4,
                                                         float* __restrict__ rawP,
                                                         float* __restrict__ CpreP,
                                                         float* __restrict__ q_scores,
                                                         float* __restrict__ A1) {
    extern __shared__ char smem[];
    const int bx = blockIdx.x;
    const int tid = threadIdx.x;
    const int lane = tid & 63;
    const int w = tid >> 6;

    if (bx >= kB * kH * (kS / 16)) {
        // ---- attn4_prep path: panel = (bx-512)*4 + w ----
        const int panel = (bx - kB * kH * (kS / 16)) * 4 + w;
        const int h = panel & (kH - 1);
        const int bnk = panel >> 3;
        const int nk = bnk & (kNK - 1);
        const int b = bnk >> 4;
        const float* Kp = K4 + (size_t)(b * kH + h) * kS * kDK;
        float qv[kDK];
        const float* Qr = Q4 + (size_t)nk * kD + h * kDK;
#pragma unroll
        for (int d = 0; d < kDK; ++d) qv[d] = Qr[d];

        const int k0 = lane * 8;
        float raw[8];
        float m = -3e38f;
#pragma unroll
        for (int j = 0; j < 8; ++j) {
            const float* kr = Kp + (size_t)(k0 + j) * kDK;
            float s = 0.f;
#pragma unroll
            for (int d4 = 0; d4 < 8; ++d4) {
                f32x4 kv = *(const f32x4*)(kr + d4 * 4);
                s = fmaf(qv[d4 * 4 + 0], kv[0], s);
                s = fmaf(qv[d4 * 4 + 1], kv[1], s);
                s = fmaf(qv[d4 * 4 + 2], kv[2], s);
                s = fmaf(qv[d4 * 4 + 3], kv[3], s);
            }
            raw[j] = s * kScale;
            m = fmaxf(m, raw[j]);
        }
        m = wave_max64(m);
        float E[8];
        float s = 0.f;
#pragma unroll
        for (int j = 0; j < 8; ++j) { E[j] = __expf(raw[j] - m); s += E[j]; }
        float inc = s;
#pragma unroll
        for (int off = 1; off < 64; off <<= 1) {
            float t2 = __shfl_up(inc, off);
            if (lane >= off) inc += t2;
        }
        float run = inc - s;
        float cp[8];
#pragma unroll
        for (int j = 0; j < 8; ++j) { run += E[j]; cp[j] = run; }

        float* rrow = rawP + (size_t)panel * kS + k0;
        float* crow = CpreP + (size_t)panel * kS + k0;
        *(f32x4*)(rrow) = *(f32x4*)(raw);
        *(f32x4*)(rrow + 4) = *(f32x4*)(raw + 4);
        *(f32x4*)(crow) = *(f32x4*)(cp);
        *(f32x4*)(crow + 4) = *(f32x4*)(cp + 4);
        return;
    }

    // ---- attn1 path ----
    float* Sl = (float*)smem;        // [16][kSL] f32 = 33792 B
    u16* Pl = (u16*)smem;            // aliases Sl after barrier

    const int bh = bx >> 5;                  // kS/16 = 32 chunks
    const int q0 = (bx & 31) * 16;
    const int h = bh & (kH - 1);
    const float* Kb = Q1 + (size_t)bh * kS * kDK;   // K == Q

    {
        const int qrow = q0 + (lane & 15);
        const int dof = (lane >> 4) * 8;
        f32x4 qa = *(const f32x4*)(Kb + (size_t)qrow * kDK + dof);
        f32x4 qb = *(const f32x4*)(Kb + (size_t)qrow * kDK + dof + 4);
        s16x8 aq_h, aq_l;
#pragma unroll
        for (int j = 0; j < 4; ++j) {
            float f = qa[j];
            u16 hi = f2bf(f);
            aq_h[j] = (short)hi;
            aq_l[j] = (short)f2bf(f - bf2f(hi));
            f = qb[j];
            hi = f2bf(f);
            aq_h[4 + j] = (short)hi;
            aq_l[4 + j] = (short)f2bf(f - bf2f(hi));
        }
        for (int kt = w * 8; kt < w * 8 + 8; ++kt) {
            const int krow = kt * 16 + (lane & 15);
            f32x4 ka = *(const f32x4*)(Kb + (size_t)krow * kDK + dof);
            f32x4 kb2 = *(const f32x4*)(Kb + (size_t)krow * kDK + dof + 4);
            s16x8 bk_h, bk_l;
#pragma unroll
            for (int j = 0; j < 4; ++j) {
                float f = ka[j];
                u16 hi = f2bf(f);
                bk_h[j] = (short)hi;
                bk_l[j] = (short)f2bf(f - bf2f(hi));
                f = kb2[j];
                hi = f2bf(f);
                bk_h[4 + j] = (short)hi;
                bk_l[4 + j] = (short)f2bf(f - bf2f(hi));
            }
            f32x4 acc = {0.f, 0.f, 0.f, 0.f};
            acc = __builtin_amdgcn_mfma_f32_16x16x32_bf16(aq_h, bk_h, acc, 0, 0, 0);
            acc = __builtin_amdgcn_mfma_f32_16x16x32_bf16(aq_l, bk_h, acc, 0, 0, 0);
            acc = __builtin_amdgcn_mfma_f32_16x16x32_bf16(aq_h, bk_l, acc, 0, 0, 0);
            const int colk = kt * 16 + (lane & 15);
            const int seg = colk >> 5, ii = colk & 31;
#pragma unroll
            for (int j = 0; j < 4; ++j) {
                const int row = (lane >> 4) * 4 + j;
                Sl[row * kSL + seg * 33 + ii] = acc[j] * kScale;
            }
        }
    }
    __syncthreads();

    const float gh = -fabsf(gam[h]);
    const int r = tid >> 4, seg16 = tid & 15;
    const int q = q0 + r, L = q + 1, ks = seg16 * 32;
    float sv[32];
    {
        const float* srow = Sl + r * kSL + seg16 * 33;
#pragma unroll
        for (int i = 0; i < 32; ++i) sv[i] = srow[i];
    }
    __syncthreads();
    {
        const int nv = min(max(L - ks, 0), 32);
        float m = -3e38f;
#pragma unroll
        for (int i = 0; i < 32; ++i)
            if (i < nv) m = fmaxf(m, sv[i]);
#pragma unroll
        for (int off = 1; off < 16; off <<= 1) m = fmaxf(m, __shfl_xor(m, off));
        float segsum = 0.f;
#pragma unroll
        for (int i = 0; i < 32; ++i)
            if (i < nv) segsum += __expf(sv[i] - m);
        float tot = segsum;
#pragma unroll
        for (int off = 1; off < 16; off <<= 1) tot += __shfl_xor(tot, off);
        float inc = segsum;
#pragma unroll
        for (int off = 1; off < 16; off <<= 1) {
            const float tmp = __shfl_up(inc, off);
            if ((tid & 15) >= off) inc += tmp;
        }
        float run = inc - segsum;
        const float inv_tot = 1.f / tot;
        float m2 = -3e38f;
#pragma unroll
        for (int i = 0; i < 32; ++i) {
            if (i < nv) {
                const float E = __expf(sv[i] - m);
                run += E;
                const float rem = 1.f - run * inv_tot;
                const float pos = (float)(q - (ks + i));
                const float val = fmaxf(rem * pos, 0.f);
                const float te = fmaxf(__expf(gh * sqrtf(val)), 1e-5f);
                const float s2 = sv[i] * te;
                sv[i] = s2;
                m2 = fmaxf(m2, s2);
            }
        }
#pragma unroll
        for (int off = 1; off < 16; off <<= 1) m2 = fmaxf(m2, __shfl_xor(m2, off));
        float sum2 = 0.f;
#pragma unroll
        for (int i = 0; i < 32; ++i) {
            const float p = (i < nv) ? __expf(sv[i] - m2) : 0.f;
            sv[i] = p;
            sum2 += p;
        }
#pragma unroll
        for (int off = 1; off < 16; off <<= 1) sum2 += __shfl_xor(sum2, off);
        const float inv2 = 1.f / sum2;
        float* qrow = q_scores + ((size_t)bh * kS + q) * kS + ks;
        u16* prow = Pl + r * kPS + ks;
#pragma unroll
        for (int i = 0; i < 32; i += 4) {
            f32x4 o;
            u16x4 pb;
#pragma unroll
            for (int j = 0; j < 4; ++j) {
                const float p = sv[i + j] * inv2;
                o[j] = p;
                pb[j] = f2bf(p);
            }
            *(f32x4*)(qrow + i) = o;
            *(u16x4*)(prow + i) = pb;
        }
    }
    __syncthreads();

    if (w < 2) {
        const int dt = w;
        const u16* Arow = Pl + (size_t)(lane & 15) * kPS + (lane >> 4) * 8;
        const u16* Brow = Vtg1 + ((size_t)bh * kDK + dt * 16 + (lane & 15)) * kS + (lane >> 4) * 8;
        f32x4 acc = {0.f, 0.f, 0.f, 0.f};
#pragma unroll
        for (int kc = 0; kc < kS; kc += 32) {
            s16x8 a = *(const s16x8*)(Arow + kc);
            s16x8 b = *(const s16x8*)(Brow + kc);
            acc = __builtin_amdgcn_mfma_f32_16x16x32_bf16(a, b, acc, 0, 0, 0);
        }
        const int d = dt * 16 + (lane & 15);
#pragma unroll
        for (int j = 0; j < 4; ++j) {
            const int row = (lane >> 4) * 4 + j;
            A1[((size_t)bh * kS + (q0 + row)) * kDK + d] = acc[j];
        }
    }
}

// Block-4 main: fused single-pass softmax; plain stores; PV B from global Vtg
__global__ __launch_bounds__(256) void attn4_main(const float* __restrict__ rawP,
                                                  const float* __restrict__ CpreP,
                                                  const u16* __restrict__ Vtg,
                                                  const float* __restrict__ gam,
                                                  float* __restrict__ k_scores,
                                                  float* __restrict__ A4) {
    extern __shared__ char smem[];
    u16* Pl = (u16*)smem;                           // [32][kPS] bf16
    float* raws_l = (float*)(smem + 32 * kPS * 2);  // [512]
    float* cps_l = raws_l + kS;                     // [512]

    const int panel = blockIdx.x;
    const int q0 = blockIdx.y * 32;
    const int h = panel & (kH - 1);
    const int bnk = panel >> 3;
    const int nk = bnk & (kNK - 1);
    const int b = bnk >> 4;
    const int tid = threadIdx.x;
    const int lane = tid & 63;
    const int w = tid >> 6;

    for (int i = tid; i < kS; i += 256) {
        raws_l[i] = rawP[(size_t)panel * kS + i];
        cps_l[i] = CpreP[(size_t)panel * kS + i];
    }
    __syncthreads();

    const float gh = -fabsf(gam[h]);
    const int rbase = w * 8;
    const int k0 = lane * 8;
    float rw[8], cp[8];
    *(f32x4*)(rw) = *(const f32x4*)(raws_l + k0);
    *(f32x4*)(rw + 4) = *(const f32x4*)(raws_l + k0 + 4);
    *(f32x4*)(cp) = *(const f32x4*)(cps_l + k0);
    *(f32x4*)(cp + 4) = *(const f32x4*)(cps_l + k0 + 4);

    for (int r = 0; r < 8; ++r) {
        const int row = rbase + r;
        const int Lr = q0 + row;
        float* krow = k_scores + ((size_t)((b * kH + h) * kS + Lr) * kNK + nk) * kS;
        u16* prow = Pl + (size_t)row * kPS + k0;
        if (Lr == 0) {
            f32x4 z = {0.f, 0.f, 0.f, 0.f};
            *(f32x4*)(krow + k0) = z;
            *(f32x4*)(krow + k0 + 4) = z;
            u16x8 zb = {0, 0, 0, 0, 0, 0, 0, 0};
            *(u16x8*)(prow) = zb;
            continue;
        }
        const float invCL = 1.f / cps_l[Lr - 1];
        const float fL = (float)(Lr - k0);
        float s2v[8];
        float mloc = -3e38f;
#pragma unroll
        for (int j = 0; j < 8; ++j) {
            const float rem = 1.f - cp[j] * invCL;
            const float val = fmaxf(rem * (fL - (float)j), 0.f);
            const float te = fmaxf(__expf(gh * sqrtf(val)), 1e-5f);
            const float s2 = rw[j] * te;
            s2v[j] = s2;
            if (k0 + j < Lr) mloc = fmaxf(mloc, s2);
        }
        const float m2 = wave_max64(mloc);
        float p[8];
        float psum = 0.f;
#pragma unroll
        for (int j = 0; j < 8; ++j) {
            p[j] = (k0 + j < Lr) ? __expf(s2v[j] - m2) : 0.f;
            psum += p[j];
        }
        const float sum2 = wave_sum64(psum);
        const float scl = fminf(sum2, 5.f) / sum2;
        u16x8 pb;
#pragma unroll
        for (int j = 0; j < 8; ++j) {
            p[j] *= scl;
            pb[j] = f2bf(p[j]);
        }
        *(f32x4*)(krow + k0) = *(f32x4*)(p);
        *(f32x4*)(krow + k0 + 4) = *(f32x4*)(p + 4);
        *(u16x8*)(prow) = pb;
    }
    __syncthreads();

    const int rowblk = (w & 1) * 16;
    const int dblk = (w >> 1) * 16;
    const u16* Arow = Pl + (size_t)(rowblk + (lane & 15)) * kPS + (lane >> 4) * 8;
    const u16* Brow = Vtg + ((size_t)(b * kH + h) * kDK + dblk + (lane & 15)) * kS + (lane >> 4) * 8;
    f32x4 acc = {0.f, 0.f, 0.f, 0.f};
#pragma unroll
    for (int kc = 0; kc < kS; kc += 32) {
        s16x8 a = *(const s16x8*)(Arow + kc);
        s16x8 bfr = *(const s16x8*)(Brow + kc);
        acc = __builtin_amdgcn_mfma_f32_16x16x32_bf16(a, bfr, acc, 0, 0, 0);
    }
    const int d = dblk + (lane & 15);
#pragma unroll
    for (int j = 0; j < 4; ++j) {
        const int row = rowblk + (lane >> 4) * 4 + j;
        A4[((size_t)panel * kS + (q0 + row)) * kDK + d] = acc[j];
    }
}

extern "C" void kernel_launch(void* const* d_in, const int* in_sizes, int n_in,
                              void* d_out, int out_size, void* d_ws, size_t ws_size,
                              hipStream_t stream) {
    (void)in_sizes; (void)n_in; (void)out_size; (void)ws_size;

    const float* q_emb = (const float*)d_in[0];
    const float* s_emb = (const float*)d_in[1];
    const float* Wq1 = (const float*)d_in[5];  const float* bq1 = (const float*)d_in[6];
    const float* Wv1 = (const float*)d_in[7];  const float* bv1 = (const float*)d_in[8];
    const float* Wo1 = (const float*)d_in[9];  const float* bo1 = (const float*)d_in[10];
    const float* gam1 = (const float*)d_in[11];
    const float* ln1g = (const float*)d_in[12]; const float* ln1b = (const float*)d_in[13];
    const float* Wq4 = (const float*)d_in[14]; const float* bq4 = (const float*)d_in[15];
    const float* Wk4 = (const float*)d_in[16]; const float* bk4 = (const float*)d_in[17];
    const float* Wv4 = (const float*)d_in[18]; const float* bv4 = (const float*)d_in[19];
    const float* Wo4 = (const float*)d_in[20]; const float* bo4 = (const float*)d_in[21];
    const float* gam4 = (const float*)d_in[22];
    const float* ln4g = (const float*)d_in[23]; const float* ln4b = (const float*)d_in[24];
    const float* know = (const float*)d_in[25];

    float* ws = (float*)d_ws;
    const size_t NBHSD = (size_t)kB * kH * kS * kDK;       // 262144
    float* Q1 = ws;
    float* RAW = Q1 + NBHSD;                                // rawP+CpreP = 262144 floats
    float* A1 = RAW + NBHSD;
    float* K4 = A1 + NBHSD;
    float* Q4 = K4 + NBHSD;                                 // NK*D = 4096
    float* A4 = Q4 + (size_t)kNK * kD;                      // 4194304
    float* WT = A4 + (size_t)kB * kNK * kH * kS * kDK;      // 7 * 65536 floats
    u16* Vtg = (u16*)(WT + 7 * (size_t)kD * kD);            // 262144 u16
    u16* Vtg1 = Vtg + (size_t)kB * kH * kDK * kS;           // 262144 u16

    float* rawP = RAW;                                      // 131072 floats
    float* CpreP = RAW + (size_t)kB * kNK * kH * kS;        // +131072

    float* WTq1 = WT + 0 * (size_t)kD * kD;
    float* WTv1 = WT + 1 * (size_t)kD * kD;
    float* WTo1 = WT + 2 * (size_t)kD * kD;
    float* WTk4 = WT + 3 * (size_t)kD * kD;
    float* WTv4 = WT + 4 * (size_t)kD * kD;
    float* WTo4 = WT + 5 * (size_t)kD * kD;
    float* WTq4 = WT + 6 * (size_t)kD * kD;

    float* zout = (float*)d_out;
    float* q_scores = zout + (size_t)kB * kS * kNK * kD;
    float* k_scores = q_scores + (size_t)kB * kH * kS * kS;

    // 1. weight transposes (7 matrices)
    {
        dim3 g(64, 7);
        wt_kernel<<<g, 256, 0, stream>>>(Wq1, Wv1, Wo1, Wk4, Wv4, Wo4, Wq4, WT);
    }
    // 2. batched projections: Q1, Vtg1(bf16T), K4, Q4
    {
        dim3 g(kB * kS / 4, 4);
        gemm256_b4<<<g, 256, 0, stream>>>(q_emb, s_emb, know,
                                          WTq1, bq1, WTv1, bv1, WTk4, bk4, WTq4, bq4,
                                          Q1, Vtg1, K4, Q4);
    }
    // 3. fused block-1 attention + block-4 prep
    {
        const int nb1 = kB * kH * (kS / 16);                // 512
        const int nbp = kB * kNK * kH / 4;                  // 64
        const int lds1 = 16 * kSL * 4;                      // 33792
        attn1_prep_kernel<<<nb1 + nbp, 256, lds1, stream>>>(Q1, Vtg1, gam1, Q4, K4,
                                                            rawP, CpreP, q_scores, A1);
    }
    // 4. fused epi1 + V4 proj + V transpose -> Vtg
    epi1v4_kernel<<<kB * kS / 4, 256, 0, stream>>>(A1, q_emb, WTo1, bo1, ln1g, ln1b,
                                                   WTv4, bv4, Vtg);
    // 5. block-4 attention
    {
        dim3 g5(kB * kNK * kH, kS / 32);
        const int lds_bytes = 32 * kPS * 2 + 2 * kS * 4;    // 37376
        attn4_main<<<g5, 256, lds_bytes, stream>>>(rawP, CpreP, Vtg, gam4, k_scores, A4);
    }
    // 6. block-4 epilogue
    gemm256<4, 2><<<kB * kNK * kS / 16, 256, 0, stream>>>(A4, WTo4, bo4, know, ln4g, ln4b, zout);
}